// Round 9
// baseline (1004.717 us; speedup 1.0000x reference)
//
#include <hip/hip_runtime.h>

typedef unsigned int uint;
typedef unsigned short ushort_t;

#define NB 512      // batch
#define NK 1152     // input capsules
#define ND 8        // in dim
#define NU 16       // out dim
#define NJ 10       // output capsules
#define NPH 30      // routing phases (NJ * 3)
#define EPSQ 1e-7f

#define TPB 512     // threads per fused block (8 waves)
#define KPT 3       // max k per thread: ceil(1152/512); tid<128 do 3rd

// ws layout (floats)
#define OFF_DP 0                          // dp[NPH][NK] per-phase agree deltas
#define OFF_BLF (NPH * NK)                // blf[NJ][NK] finalized logit columns
#define OFF_XB (OFF_BLF + NJ * NK)        // Xb bf16 [NB][NK][ND]
#define OFF_WTB (OFF_XB + (NB*NK*ND)/2)   // WTb bf16 [NJ][NU][NK][ND]
// total ~12.5 MB << ws

// fp32 -> bf16 RNE (values are finite/normal here)
__device__ __forceinline__ ushort_t b16(float f) {
  uint u = __float_as_uint(f);
  return (ushort_t)((u + 0x7fffu + ((u >> 16) & 1u)) >> 16);
}
// unpack 8 bf16 (uint4) -> 8 fp32
__device__ __forceinline__ void up8(const uint4 v, float* f) {
  f[0] = __uint_as_float(v.x << 16); f[1] = __uint_as_float(v.x & 0xffff0000u);
  f[2] = __uint_as_float(v.y << 16); f[3] = __uint_as_float(v.y & 0xffff0000u);
  f[4] = __uint_as_float(v.z << 16); f[5] = __uint_as_float(v.z & 0xffff0000u);
  f[6] = __uint_as_float(v.w << 16); f[7] = __uint_as_float(v.w & 0xffff0000u);
}
__device__ __forceinline__ float dot8(const float* a, const float* b) {
  return a[0]*b[0] + a[1]*b[1] + a[2]*b[2] + a[3]*b[3] +
         a[4]*b[4] + a[5]*b[5] + a[6]*b[6] + a[7]*b[7];
}

// ---------------------------------------------------------------------------
// init: zero dp; build Xb[b][k][d] (bf16) and WTb[j][u][k][d] (bf16).
// WTb u-major over k -> per-u W load coalesced (lane t reads k=t).
// ---------------------------------------------------------------------------
__global__ __launch_bounds__(256) void caps_init(const float* __restrict__ x,
                                                 const float* __restrict__ W,
                                                 float* __restrict__ dp,
                                                 ushort_t* __restrict__ Xb,
                                                 ushort_t* __restrict__ WTb) {
  const int g = blockIdx.x * 256 + threadIdx.x;
  if (g < NPH * NK) dp[g] = 0.f;
  if (g < (NB * NK * ND) / 8) {  // 589824 groups of 8
    const float4* xp = (const float4*)x + (size_t)g * 2;
    const float4 a = xp[0], b = xp[1];
    uint4 o;
    o.x = (uint)b16(a.x) | ((uint)b16(a.y) << 16);
    o.y = (uint)b16(a.z) | ((uint)b16(a.w) << 16);
    o.z = (uint)b16(b.x) | ((uint)b16(b.y) << 16);
    o.w = (uint)b16(b.z) | ((uint)b16(b.w) << 16);
    ((uint4*)Xb)[g] = o;
  }
  if (g < (NJ * NK * NU * ND) / 8) {  // 184320 groups: g = ((j*NU)+u)*NK + k
    const int k = g % NK;
    const int u = (g / NK) % NU;
    const int j = g / (NK * NU);
    const float* wp = W + ((size_t)(j * NK + k) * ND) * NU + u;  // d-stride NU
    uint4 o;
    o.x = (uint)b16(wp[0])  | ((uint)b16(wp[16]) << 16);
    o.y = (uint)b16(wp[32]) | ((uint)b16(wp[48]) << 16);
    o.z = (uint)b16(wp[64]) | ((uint)b16(wp[80]) << 16);
    o.w = (uint)b16(wp[96]) | ((uint)b16(wp[112]) << 16);
    ((uint4*)WTb)[g] = o;  // [j][u][k] row of 8 d's
  }
}

// ---------------------------------------------------------------------------
// caps_fused: ONE launch per routing phase; RACE-FREE by construction.
// r6/r7 had a latent intra-launch race (softmax read bl while same-launch
// agree atomicAdd'd it; survived only by block-lockstep timing luck — r8's
// reorder + 512 blocks broke the luck). Now: agree writes go to a fresh
// per-phase delta buffer dp[n] (write-only this launch); softmax rebuilds
// logits from launch-stable buffers: finalized columns blf[jj<j], current
// column from dp[3j](+dp[3j+1]). At t==0 all blocks materialize
// blf[j-1] = dp[3j-3]+dp[3j-2]+dp[3j-1] (bitwise-identical redundant
// stores; first read is next launch). No buffer is read+written with
// differing values in one launch -> correct under any block skew.
// 512 blocks x 512 thr, uh[3][16]=48 VGPR, launch_bounds(512,4):
// 2 blocks/CU, 4 waves/SIMD. All global loads coalesced.
// ---------------------------------------------------------------------------
__global__ __launch_bounds__(TPB, 4) void caps_fused(
    const ushort_t* __restrict__ Xb, const ushort_t* __restrict__ WTb,
    float* __restrict__ dp, float* __restrict__ blf, float* __restrict__ out,
    int n, int j, int t, int writeOut, int doAgree) {
  __shared__ float c_lds[NK];                 // 4608 B softmax coefficients
  __shared__ float sred[8][NU];               // 512 B cross-wave s partials
  __shared__ float sv[NU];                    // 64 B squashed v
  const int tid = threadIdx.x;
  const int lane = tid & 63;
  const int w = tid >> 6;
  const int b = blockIdx.x;
  const int jm1 = j - 1;

  // --- pass 1: uh[k][u] in registers (independent of softmax)
  const uint4* xrow = (const uint4*)Xb + (size_t)b * NK;
  const uint4* wplane = (const uint4*)WTb + (size_t)j * NU * NK;
  float uh[KPT][NU];                          // 48 VGPR
#pragma unroll
  for (int i = 0; i < KPT; ++i) {
    const int k = tid + i * TPB;
    if (k < NK) {
      float xd[8];
      up8(xrow[k], xd);
#pragma unroll
      for (int u = 0; u < NU; ++u) {
        float wd[8];
        up8(wplane[(size_t)u * NK + k], wd);   // coalesced: lane t -> k=t
        uh[i][u] = dot8(xd, wd);
      }
    } else {
#pragma unroll
      for (int u = 0; u < NU; ++u) uh[i][u] = 0.f;
    }
  }

  // --- softmax coefficients from launch-stable buffers (block-redundant)
  for (int k = tid; k < NK; k += TPB) {
    float r[NJ];        // all indices compile-time (unrolled) -> registers
    float fnew = 0.f;   // blf[j-1] materialization value (t==0)
    float valj = 0.f;   // r[j] without dynamic indexing
#pragma unroll
    for (int jj = 0; jj < NJ; ++jj) {
      float v = 0.f;
      if (jj < j) {          // finalized column (uniform scalar predicates)
        if (t == 0 && jj == jm1) {
          fnew = dp[(size_t)(3 * jm1) * NK + k] +
                 dp[(size_t)(3 * jm1 + 1) * NK + k] +
                 dp[(size_t)(3 * jm1 + 2) * NK + k];
          v = fnew;
        } else {
          v = blf[(size_t)jj * NK + k];
        }
      } else if (jj == j) {  // current column partial (t deltas so far)
        if (t >= 1) v = dp[(size_t)(3 * j) * NK + k];
        if (t == 2) v += dp[(size_t)(3 * j + 1) * NK + k];
      }                      // jj > j: zero
      r[jj] = v;
      if (jj == j) valj = v;
    }
    if (t == 0 && j > 0) blf[(size_t)jm1 * NK + k] = fnew;  // identical stores
    float mx = r[0];
#pragma unroll
    for (int jj = 1; jj < NJ; ++jj) mx = fmaxf(mx, r[jj]);
    float se = 0.f;
#pragma unroll
    for (int jj = 0; jj < NJ; ++jj) se += __expf(r[jj] - mx);
    c_lds[k] = __expf(valj - mx) / se;
  }
  __syncthreads();

  // --- s accumulation from cached uh
  float s[NU];
#pragma unroll
  for (int u = 0; u < NU; ++u) s[u] = 0.f;
#pragma unroll
  for (int i = 0; i < KPT; ++i) {
    const int k = tid + i * TPB;
    if (k < NK) {
      const float ck = c_lds[k];
#pragma unroll
      for (int u = 0; u < NU; ++u) s[u] = fmaf(ck, uh[i][u], s[u]);
    }
  }
  // wave-level butterfly (order 1,2,4,8,16,32)
#pragma unroll
  for (int u = 0; u < NU; ++u) {
#pragma unroll
    for (int off = 1; off < 64; off <<= 1)
      s[u] += __shfl_xor(s[u], off, 64);
  }
  if (lane == 0) {
#pragma unroll
    for (int u = 0; u < NU; ++u) sred[w][u] = s[u];
  }
  __syncthreads();

  // --- fold 8 waves + squash (tid<16, one lane per u)
  if (tid < NU) {
    float sval = 0.f;
#pragma unroll
    for (int wv = 0; wv < 8; ++wv) sval += sred[wv][tid];
    float sq = sval * sval;
    sq += __shfl_xor(sq, 1, 64);
    sq += __shfl_xor(sq, 2, 64);
    sq += __shfl_xor(sq, 4, 64);
    sq += __shfl_xor(sq, 8, 64);   // stays within lanes 0-15
    const float scale = (sq / (1.f + sq)) / (sqrtf(sq) + EPSQ);
    const float vv = scale * sval;
    sv[tid] = vv;
    if (writeOut)
      out[((size_t)b * NJ + j) * NU + tid] = vv;
  }
  __syncthreads();

  // --- agree from cached uh into FRESH dp[n] (write-only this launch)
  if (doAgree) {
    float v[NU];
#pragma unroll
    for (int u = 0; u < NU; ++u) v[u] = sv[u];
    float* drow = dp + (size_t)n * NK;
#pragma unroll
    for (int i = 0; i < KPT; ++i) {
      const int k = tid + i * TPB;
      if (k < NK) {
        float ag = 0.f;
#pragma unroll
        for (int u = 0; u < NU; ++u) ag += uh[i][u] * v[u];
        atomicAdd(&drow[k], ag);   // coalesced: lane t -> k=t
      }
    }
  }
}

// ---------------------------------------------------------------------------
extern "C" void kernel_launch(void* const* d_in, const int* in_sizes, int n_in,
                              void* d_out, int out_size, void* d_ws,
                              size_t ws_size, hipStream_t stream) {
  (void)in_sizes; (void)n_in; (void)out_size; (void)ws_size;
  const float* x = (const float*)d_in[0];   // [512][1152][8][1] fp32
  const float* W = (const float*)d_in[1];   // [10][1152][8][16] fp32
  float* out = (float*)d_out;               // [512][10][16][1] fp32
  float* ws = (float*)d_ws;
  float* dp  = ws + OFF_DP;                 // [NPH][NK]
  float* blf = ws + OFF_BLF;                // [NJ][NK]
  ushort_t* Xb  = (ushort_t*)(ws + OFF_XB);
  ushort_t* WTb = (ushort_t*)(ws + OFF_WTB);

  caps_init<<<(NB * NK * ND / 8 + 255) / 256, 256, 0, stream>>>(x, W, dp, Xb,
                                                                WTb);
  for (int n = 0; n < NPH; ++n) {
    const int j = n / 3;
    const int t = n - 3 * j;
    caps_fused<<<NB, TPB, 0, stream>>>(Xb, WTb, dp, blf, out, n, j, t,
                                       (t == 2) ? 1 : 0,
                                       (n < NPH - 1) ? 1 : 0);
  }
}